// Round 7
// baseline (196.403 us; speedup 1.0000x reference)
//
#include <hip/hip_runtime.h>

#define NB 32
#define LL 2048
#define CH 512
#define BQ 512
#define HH 1024
#define LDA2 260   // K-chunk row stride (bf16): 256+4 -> 520 B rows, measured conflict-free

typedef __attribute__((ext_vector_type(8))) short bf16x8;
typedef __attribute__((ext_vector_type(16))) float f32x16;

__device__ __forceinline__ unsigned short f2bf(float x) {
  unsigned int u = __float_as_uint(x);
  u += 0x7FFFu + ((u >> 16) & 1u);   // round-to-nearest-even
  return (unsigned short)(u >> 16);
}

__device__ __forceinline__ unsigned int cvt_pk_bf16(float a, float b) {
  unsigned int r;
  asm("v_cvt_pk_bf16_f32 %0, %1, %2" : "=v"(r) : "v"(a), "v"(b));
  return r;   // lo16 = bf16(a), hi16 = bf16(b)
}

__device__ __forceinline__ float fast_tanh(float x) {
  // tanh(x) = 1 - 2/(exp2(2*log2e*x)+1); saturates correctly at +-inf
  float e = __builtin_amdgcn_exp2f(x * 2.885390081777927f);
  return 1.0f - 2.0f * __builtin_amdgcn_rcpf(e + 1.0f);
}

// ---------------- res_qc[b][h] = query[b,:]·Wq[h,:] + bc[h] ----------------
__global__ __launch_bounds__(256) void k_resqc(const float* __restrict__ query,
                                               const float* __restrict__ Wq,
                                               const float* __restrict__ bc,
                                               float* __restrict__ resqc) {
  int gid = blockIdx.x * 256 + threadIdx.x;   // 32768
  int b = gid >> 10, h = gid & 1023;
  const float4* q4 = (const float4*)(query + (size_t)b * BQ);
  const float4* w4 = (const float4*)(Wq + (size_t)h * BQ);
  float acc = 0.f;
#pragma unroll 4
  for (int i = 0; i < BQ / 4; ++i) {
    float4 a = q4[i], w = w4[i];
    acc += a.x * w.x + a.y * w.y + a.z * w.z + a.w * w.w;
  }
  resqc[gid] = acc + bc[h];
}

// ---------------- Wc f32 -> bf16, packed in MFMA B-fragment order ----------------
// wcbp[cg][ks][lane][8] : lane=(lo,hi) gets Wc[cg*32+lo][hi*8 + ks*16 .. +8]
__global__ __launch_bounds__(256) void k_pack_wc(const float* __restrict__ Wc,
                                                 unsigned short* __restrict__ wcbp) {
  int gid = blockIdx.x * 256 + threadIdx.x;   // 65536 = 32 cg * 32 ks * 64 lanes
  int lane = gid & 63, ks = (gid >> 6) & 31, cg = gid >> 11;
  int lo = lane & 31, hi = lane >> 5;
  const float4* s = (const float4*)(Wc + (size_t)(cg * 32 + lo) * CH + hi * 8 + ks * 16);
  float4 v0 = s[0], v1 = s[1];
  union { unsigned short s[8]; uint4 u; } p;
  p.s[0] = f2bf(v0.x); p.s[1] = f2bf(v0.y); p.s[2] = f2bf(v0.z); p.s[3] = f2bf(v0.w);
  p.s[4] = f2bf(v1.x); p.s[5] = f2bf(v1.y); p.s[6] = f2bf(v1.z); p.s[7] = f2bf(v1.w);
  ((uint4*)wcbp)[gid] = p.u;
}

// epilogue: tanh + Wo-weighted col-sum for one N-half; register-only + lsum atomics
__device__ __forceinline__ void epilogue(const f32x16 (&acc)[4][2], int nh,
                                         int wave, int lo, int hi,
                                         const float* __restrict__ resqc_b,
                                         const float* __restrict__ Wo,
                                         float* __restrict__ lsum) {
  int c0 = nh * 512 + wave * 64;
  float q0 = resqc_b[c0 + lo],  q1 = resqc_b[c0 + 32 + lo];
  float w0 = Wo[c0 + lo],       w1 = Wo[c0 + 32 + lo];
#pragma unroll
  for (int half = 0; half < 2; ++half) {   // row-frags m = 2*half + {0,1}
    float v[32];
#pragma unroll
    for (int mm = 0; mm < 2; ++mm)
#pragma unroll
      for (int r = 0; r < 16; ++r)
        v[mm * 16 + r] = w0 * fast_tanh(acc[half * 2 + mm][0][r] + q0)
                       + w1 * fast_tanh(acc[half * 2 + mm][1][r] + q1);
    // transpose-reduce: after 5 levels lane lo holds the 32-lane sum of value lo
#pragma unroll
    for (int s = 16; s >= 1; s >>= 1) {
#pragma unroll
      for (int i = 0; i < s; ++i) {
        float a = v[i], c = v[i + s];
        float keep = (lo & s) ? c : a;
        float send = (lo & s) ? a : c;
        v[i] = keep + __shfl_xor(send, s, 64);
      }
    }
    int rr = lo & 15;
    int m = half * 2 + (lo >> 4);
    int row = m * 32 + (rr & 3) + 8 * (rr >> 2) + 4 * hi;   // verified C/D row map
    atomicAdd(&lsum[row], v[0]);
  }
}

// ---------------- main: logits[b][l] = sum_h Wo[h]*tanh(resqc[b][h] + ctx[b,l,:]·Wc[h,:])
// 512 blocks x 512 thr (8 waves). Block = 128 rows x K=512 (two K-chunk LDS bufs)
// x N=1024 in two 512-col halves. acc[4][2] f32x16 = 128 regs (budget 256 via
// launch_bounds(512,2)). K1 staging interleaved into NH0-K0 compute.
__global__ __launch_bounds__(512, 2) void k_logits(const float* __restrict__ ctx,
                                                   const unsigned short* __restrict__ wcbp,
                                                   const float* __restrict__ resqc,
                                                   const float* __restrict__ Wo,
                                                   float* __restrict__ logits) {
  __shared__ unsigned short A0[128 * LDA2];   // K-chunk 0 (cols 0..255), 66560 B
  __shared__ unsigned short A1[128 * LDA2];   // K-chunk 1 (cols 256..511)
  __shared__ float lsum[128];

  const int t = threadIdx.x;
  const int g = blockIdx.x;          // 512 row-tiles
  const int b = g >> 4, row0 = (g & 15) << 7;

  if (t < 128) lsum[t] = 0.f;

  const float4* src = (const float4*)(ctx + ((size_t)(b * LL + row0)) * CH);  // row = 128 float4

  // S0: stage K-chunk 0 -> A0 (coalesced: each wave writes full 1KB row-segments)
#pragma unroll
  for (int i = 0; i < 16; ++i) {
    int f = i * 512 + t;
    int r = f >> 6, c4 = f & 63;
    float4 v = src[(size_t)r * 128 + c4];
    uint2 w;
    w.x = cvt_pk_bf16(v.x, v.y);
    w.y = cvt_pk_bf16(v.z, v.w);
    *(uint2*)(A0 + r * LDA2 + c4 * 4) = w;
  }
  __syncthreads();

  const int wave = t >> 6, lane = t & 63;
  const int lo = lane & 31, hi = lane >> 5;
  const float* resqc_b = resqc + b * HH;
  const uint4* bW = (const uint4*)wcbp;

  const char* a0 = (const char*)A0 + lo * (LDA2 * 2) + hi * 16;
  const char* a1 = (const char*)A1 + lo * (LDA2 * 2) + hi * 16;

  f32x16 acc[4][2];

  // ---- NH0 (cols 0..511): cg = wave*2 + n ----
#pragma unroll
  for (int m = 0; m < 4; ++m)
#pragma unroll
    for (int n = 0; n < 2; ++n) acc[m][n] = (f32x16){0,0,0,0,0,0,0,0,0,0,0,0,0,0,0,0};

  // Q1: NH0 x K0, one K1-staging step per ks (store to A1; no barrier needed)
#pragma unroll
  for (int ks = 0; ks < 16; ++ks) {
    {
      int f = ks * 512 + t;
      int r = f >> 6, c4 = f & 63;
      float4 v = src[(size_t)r * 128 + 64 + c4];
      uint2 w;
      w.x = cvt_pk_bf16(v.x, v.y);
      w.y = cvt_pk_bf16(v.z, v.w);
      *(uint2*)(A1 + r * LDA2 + c4 * 4) = w;
    }
    uint4 ub0 = bW[(size_t)((wave * 2 + 0) * 32 + ks) * 64 + lane];
    uint4 ub1 = bW[(size_t)((wave * 2 + 1) * 32 + ks) * 64 + lane];
    bf16x8 fb0, fb1;
    __builtin_memcpy(&fb0, &ub0, 16);
    __builtin_memcpy(&fb1, &ub1, 16);
#pragma unroll
    for (int m = 0; m < 4; ++m) {
      bf16x8 fa = *(const bf16x8*)(a0 + m * (32 * LDA2 * 2) + ks * 32);
      acc[m][0] = __builtin_amdgcn_mfma_f32_32x32x16_bf16(fa, fb0, acc[m][0], 0, 0, 0);
      acc[m][1] = __builtin_amdgcn_mfma_f32_32x32x16_bf16(fa, fb1, acc[m][1], 0, 0, 0);
    }
  }
  __syncthreads();   // A1 complete

  // Q2: NH0 x K1
#pragma unroll 8
  for (int ks = 0; ks < 16; ++ks) {
    uint4 ub0 = bW[(size_t)((wave * 2 + 0) * 32 + 16 + ks) * 64 + lane];
    uint4 ub1 = bW[(size_t)((wave * 2 + 1) * 32 + 16 + ks) * 64 + lane];
    bf16x8 fb0, fb1;
    __builtin_memcpy(&fb0, &ub0, 16);
    __builtin_memcpy(&fb1, &ub1, 16);
#pragma unroll
    for (int m = 0; m < 4; ++m) {
      bf16x8 fa = *(const bf16x8*)(a1 + m * (32 * LDA2 * 2) + ks * 32);
      acc[m][0] = __builtin_amdgcn_mfma_f32_32x32x16_bf16(fa, fb0, acc[m][0], 0, 0, 0);
      acc[m][1] = __builtin_amdgcn_mfma_f32_32x32x16_bf16(fa, fb1, acc[m][1], 0, 0, 0);
    }
  }
  epilogue(acc, 0, wave, lo, hi, resqc_b, Wo, lsum);   // no barrier: waves drift/overlap

  // ---- NH1 (cols 512..1023): cg = 16 + wave*2 + n; K1 then K0 ----
#pragma unroll
  for (int m = 0; m < 4; ++m)
#pragma unroll
    for (int n = 0; n < 2; ++n) acc[m][n] = (f32x16){0,0,0,0,0,0,0,0,0,0,0,0,0,0,0,0};

#pragma unroll 8
  for (int ks = 0; ks < 16; ++ks) {   // Q3: NH1 x K1
    uint4 ub0 = bW[(size_t)((16 + wave * 2 + 0) * 32 + 16 + ks) * 64 + lane];
    uint4 ub1 = bW[(size_t)((16 + wave * 2 + 1) * 32 + 16 + ks) * 64 + lane];
    bf16x8 fb0, fb1;
    __builtin_memcpy(&fb0, &ub0, 16);
    __builtin_memcpy(&fb1, &ub1, 16);
#pragma unroll
    for (int m = 0; m < 4; ++m) {
      bf16x8 fa = *(const bf16x8*)(a1 + m * (32 * LDA2 * 2) + ks * 32);
      acc[m][0] = __builtin_amdgcn_mfma_f32_32x32x16_bf16(fa, fb0, acc[m][0], 0, 0, 0);
      acc[m][1] = __builtin_amdgcn_mfma_f32_32x32x16_bf16(fa, fb1, acc[m][1], 0, 0, 0);
    }
  }
#pragma unroll 8
  for (int ks = 0; ks < 16; ++ks) {   // Q4: NH1 x K0
    uint4 ub0 = bW[(size_t)((16 + wave * 2 + 0) * 32 + ks) * 64 + lane];
    uint4 ub1 = bW[(size_t)((16 + wave * 2 + 1) * 32 + ks) * 64 + lane];
    bf16x8 fb0, fb1;
    __builtin_memcpy(&fb0, &ub0, 16);
    __builtin_memcpy(&fb1, &ub1, 16);
#pragma unroll
    for (int m = 0; m < 4; ++m) {
      bf16x8 fa = *(const bf16x8*)(a0 + m * (32 * LDA2 * 2) + ks * 32);
      acc[m][0] = __builtin_amdgcn_mfma_f32_32x32x16_bf16(fa, fb0, acc[m][0], 0, 0, 0);
      acc[m][1] = __builtin_amdgcn_mfma_f32_32x32x16_bf16(fa, fb1, acc[m][1], 0, 0, 0);
    }
  }
  epilogue(acc, 1, wave, lo, hi, resqc_b, Wo, lsum);

  __syncthreads();
  if (t < 128) logits[(size_t)b * LL + row0 + t] = lsum[t];
}

// ---------------- weights: mask*exp(logit+bo), normalize over L ----------------
__global__ __launch_bounds__(256) void k_weights(const float* __restrict__ mask,
                                                 const float* __restrict__ bo,
                                                 const float* __restrict__ logit,
                                                 float* __restrict__ wout) {
  __shared__ float red[4];
  int b = blockIdx.x, t = threadIdx.x;
  float bov = bo[0];
  float w[8];
  float s = 0.f;
#pragma unroll
  for (int i = 0; i < 8; ++i) {
    int l = t + 256 * i;
    float e = mask[b * LL + l] * __expf(logit[b * LL + l] + bov);
    w[i] = e; s += e;
  }
#pragma unroll
  for (int m = 32; m >= 1; m >>= 1) s += __shfl_xor(s, m, 64);
  int wave = t >> 6, lane = t & 63;
  if (lane == 0) red[wave] = s;
  __syncthreads();
  float inv = 1.0f / (red[0] + red[1] + red[2] + red[3] + 1e-5f);
#pragma unroll
  for (int i = 0; i < 8; ++i) wout[b * LL + t + 256 * i] = w[i] * inv;
}

// ---------------- output[b][c] = sum_l weights[b][l] * ctx[b][l][c] ----------------
__global__ __launch_bounds__(256) void k_output(const float* __restrict__ ctx,
                                                const float* __restrict__ weights,
                                                float* __restrict__ out) {
  __shared__ float wl[128];
  int bid = blockIdx.x;            // 512 = 32 b * 16 chunks
  int b = bid >> 4, chunk = bid & 15;
  int t = threadIdx.x;
  int l0 = chunk * 128;
  if (t < 128) wl[t] = weights[b * LL + l0 + t];
  __syncthreads();
  const float2* c2 = (const float2*)(ctx + ((size_t)(b * LL + l0)) * CH) + t;
  float ax = 0.f, ay = 0.f;
#pragma unroll 4
  for (int l = 0; l < 128; ++l) {
    float wv = wl[l];
    float2 v = c2[(size_t)l * (CH / 2)];
    ax += wv * v.x; ay += wv * v.y;
  }
  atomicAdd(&out[b * CH + 2 * t], ax);
  atomicAdd(&out[b * CH + 2 * t + 1], ay);
}

extern "C" void kernel_launch(void* const* d_in, const int* in_sizes, int n_in,
                              void* d_out, int out_size, void* d_ws, size_t ws_size,
                              hipStream_t stream) {
  const float* query = (const float*)d_in[0];
  const float* ctx   = (const float*)d_in[1];
  const float* mask  = (const float*)d_in[2];
  const float* Wq    = (const float*)d_in[3];
  const float* Wc    = (const float*)d_in[4];
  const float* bc    = (const float*)d_in[5];
  const float* Wo    = (const float*)d_in[6];
  const float* bo    = (const float*)d_in[7];
  float* out = (float*)d_out;

  unsigned short* wcbp = (unsigned short*)d_ws;                   // 1 MB packed bf16 Wc
  float* resqc = (float*)((char*)d_ws + (1 << 20));               // 128 KB
  float* logit = (float*)((char*)d_ws + (1 << 20) + (1 << 17));   // 32 x 2048 f32 = 256 KB
  float* wout = out + NB * CH;                                    // final weights slot

  hipMemsetAsync(out, 0, NB * CH * sizeof(float), stream);        // zero output region
  k_resqc<<<128, 256, 0, stream>>>(query, Wq, bc, resqc);
  k_pack_wc<<<256, 256, 0, stream>>>(Wc, wcbp);
  k_logits<<<512, 512, 0, stream>>>(ctx, wcbp, resqc, Wo, logit);
  k_weights<<<32, 256, 0, stream>>>(mask, bo, logit, wout);
  k_output<<<512, 256, 0, stream>>>(ctx, wout, out);
}

// Round 8
// 156.531 us; speedup vs baseline: 1.2547x; 1.2547x over previous
//
#include <hip/hip_runtime.h>

#define NB 32
#define LL 2048
#define CH 512
#define BQ 512
#define HH 1024
#define LDA2 260   // fallback-path LDS row stride

typedef __attribute__((ext_vector_type(8))) short bf16x8;
typedef __attribute__((ext_vector_type(16))) float f32x16;

__device__ __forceinline__ unsigned short f2bf(float x) {
  unsigned int u = __float_as_uint(x);
  u += 0x7FFFu + ((u >> 16) & 1u);   // round-to-nearest-even
  return (unsigned short)(u >> 16);
}

__device__ __forceinline__ unsigned int cvt_pk_bf16(float a, float b) {
  unsigned int r;
  asm("v_cvt_pk_bf16_f32 %0, %1, %2" : "=v"(r) : "v"(a), "v"(b));
  return r;   // lo16 = bf16(a), hi16 = bf16(b)
}

__device__ __forceinline__ float fast_tanh(float x) {
  float e = __builtin_amdgcn_exp2f(x * 2.885390081777927f);
  return 1.0f - 2.0f * __builtin_amdgcn_rcpf(e + 1.0f);
}

// ---------------- res_qc[b][h] = query[b,:]·Wq[h,:] + bc[h] ----------------
__global__ __launch_bounds__(256) void k_resqc(const float* __restrict__ query,
                                               const float* __restrict__ Wq,
                                               const float* __restrict__ bc,
                                               float* __restrict__ resqc) {
  int gid = blockIdx.x * 256 + threadIdx.x;   // 32768
  int b = gid >> 10, h = gid & 1023;
  const float4* q4 = (const float4*)(query + (size_t)b * BQ);
  const float4* w4 = (const float4*)(Wq + (size_t)h * BQ);
  float acc = 0.f;
#pragma unroll 4
  for (int i = 0; i < BQ / 4; ++i) {
    float4 a = q4[i], w = w4[i];
    acc += a.x * w.x + a.y * w.y + a.z * w.z + a.w * w.w;
  }
  resqc[gid] = acc + bc[h];
}

// ---------------- Wc f32 -> bf16, packed in MFMA B-fragment order ----------------
// wcbp[cg][ks][lane] : lane=(lo,hi) gets Wc[cg*32+lo][ks*16 + hi*8 .. +8]
__global__ __launch_bounds__(256) void k_pack_wc(const float* __restrict__ Wc,
                                                 unsigned short* __restrict__ wcbp) {
  int gid = blockIdx.x * 256 + threadIdx.x;   // 65536 = 32 cg * 32 ks * 64 lanes
  int lane = gid & 63, ks = (gid >> 6) & 31, cg = gid >> 11;
  int lo = lane & 31, hi = lane >> 5;
  const float4* s = (const float4*)(Wc + (size_t)(cg * 32 + lo) * CH + hi * 8 + ks * 16);
  float4 v0 = s[0], v1 = s[1];
  uint4 p;
  p.x = cvt_pk_bf16(v0.x, v0.y);
  p.y = cvt_pk_bf16(v0.z, v0.w);
  p.z = cvt_pk_bf16(v1.x, v1.y);
  p.w = cvt_pk_bf16(v1.z, v1.w);
  ((uint4*)wcbp)[gid] = p;
}

// ---------------- ctx f32 -> bf16, packed in MFMA A-fragment order ----------------
// apk[g][ks][lane] : lane=(lo,hi) gets ctx_row(g*32+lo)[ks*16 + hi*8 .. +8]
// (identical layout law as wcbp; 2048 tiles of 32 rows)
__global__ __launch_bounds__(512) void k_pack_ctx(const float* __restrict__ ctx,
                                                  uint4* __restrict__ apk) {
  int g = blockIdx.x;              // 2048 tiles
  int t = threadIdx.x;
  int lane = t & 63, ksq = t >> 6; // ksq 0..7
  int lo = lane & 31, hi = lane >> 5;
  const float* rowp = ctx + (size_t)(g * 32 + lo) * CH + hi * 8;
  uint4* dst = apk + (size_t)g * 2048 + lane;
#pragma unroll
  for (int i = 0; i < 4; ++i) {
    int ks = ksq * 4 + i;
    const float4* s = (const float4*)(rowp + ks * 16);
    float4 v0 = s[0], v1 = s[1];
    uint4 p;
    p.x = cvt_pk_bf16(v0.x, v0.y);
    p.y = cvt_pk_bf16(v0.z, v0.w);
    p.z = cvt_pk_bf16(v1.x, v1.y);
    p.w = cvt_pk_bf16(v1.z, v1.w);
    dst[(size_t)ks * 64] = p;
  }
}

// ---------------- main GEMM+tanh+reduce: no LDS, no barriers ----------------
// 2048 blocks x 256 thr (4 waves). Block = 256 rows x 128 cols; wave = 64r x 128c
// (acc[2][4] = 128 regs). A,B both pre-packed -> all loads coalesced 1KB/wave.
// Partial logits accumulated via global atomicAdd into zeroed buffer.
__global__ __launch_bounds__(256, 2) void k_logits_pk(const uint4* __restrict__ apk,
                                                      const uint4* __restrict__ bpk,
                                                      const float* __restrict__ resqc,
                                                      const float* __restrict__ Wo,
                                                      float* __restrict__ logit) {
  int bid = blockIdx.x;
  // XCD swizzle: assume xcd = blockIdx % 8; give each XCD 32 row-blocks with
  // their 8 col-chunks consecutive -> A tile read once from HBM, rest L2.
  int xcd = bid & 7, idx = bid >> 3;
  int rb = xcd * 32 + (idx >> 3), cc = idx & 7;
  int t = threadIdx.x;
  int wv = t >> 6, lane = t & 63;
  int lo = lane & 31, hi = lane >> 5;
  int b = rb >> 3;

  const uint4* pa0 = apk + (size_t)(rb * 8 + wv * 2 + 0) * 2048 + lane;
  const uint4* pa1 = apk + (size_t)(rb * 8 + wv * 2 + 1) * 2048 + lane;
  const uint4* pb0 = bpk + (size_t)(cc * 4 + 0) * 2048 + lane;
  const uint4* pb1 = bpk + (size_t)(cc * 4 + 1) * 2048 + lane;
  const uint4* pb2 = bpk + (size_t)(cc * 4 + 2) * 2048 + lane;
  const uint4* pb3 = bpk + (size_t)(cc * 4 + 3) * 2048 + lane;

  f32x16 acc[2][4];
#pragma unroll
  for (int m = 0; m < 2; ++m)
#pragma unroll
    for (int n = 0; n < 4; ++n) acc[m][n] = (f32x16){0,0,0,0,0,0,0,0,0,0,0,0,0,0,0,0};

#pragma unroll 4
  for (int ks = 0; ks < 32; ++ks) {
    uint4 ua0 = pa0[(size_t)ks * 64];
    uint4 ua1 = pa1[(size_t)ks * 64];
    uint4 ub0 = pb0[(size_t)ks * 64];
    uint4 ub1 = pb1[(size_t)ks * 64];
    uint4 ub2 = pb2[(size_t)ks * 64];
    uint4 ub3 = pb3[(size_t)ks * 64];
    bf16x8 fa0, fa1, fb0, fb1, fb2, fb3;
    __builtin_memcpy(&fa0, &ua0, 16);
    __builtin_memcpy(&fa1, &ua1, 16);
    __builtin_memcpy(&fb0, &ub0, 16);
    __builtin_memcpy(&fb1, &ub1, 16);
    __builtin_memcpy(&fb2, &ub2, 16);
    __builtin_memcpy(&fb3, &ub3, 16);
    acc[0][0] = __builtin_amdgcn_mfma_f32_32x32x16_bf16(fa0, fb0, acc[0][0], 0, 0, 0);
    acc[0][1] = __builtin_amdgcn_mfma_f32_32x32x16_bf16(fa0, fb1, acc[0][1], 0, 0, 0);
    acc[0][2] = __builtin_amdgcn_mfma_f32_32x32x16_bf16(fa0, fb2, acc[0][2], 0, 0, 0);
    acc[0][3] = __builtin_amdgcn_mfma_f32_32x32x16_bf16(fa0, fb3, acc[0][3], 0, 0, 0);
    acc[1][0] = __builtin_amdgcn_mfma_f32_32x32x16_bf16(fa1, fb0, acc[1][0], 0, 0, 0);
    acc[1][1] = __builtin_amdgcn_mfma_f32_32x32x16_bf16(fa1, fb1, acc[1][1], 0, 0, 0);
    acc[1][2] = __builtin_amdgcn_mfma_f32_32x32x16_bf16(fa1, fb2, acc[1][2], 0, 0, 0);
    acc[1][3] = __builtin_amdgcn_mfma_f32_32x32x16_bf16(fa1, fb3, acc[1][3], 0, 0, 0);
  }

  // epilogue: tanh + Wo-weighted col-sum -> 32 partials/lane, transpose-reduce
  float q_[4], wo_[4];
#pragma unroll
  for (int n = 0; n < 4; ++n) {
    q_[n]  = resqc[b * HH + cc * 128 + n * 32 + lo];
    wo_[n] = Wo[cc * 128 + n * 32 + lo];
  }
  float v[32];
#pragma unroll
  for (int m = 0; m < 2; ++m)
#pragma unroll
    for (int r = 0; r < 16; ++r) {
      float s = 0.f;
#pragma unroll
      for (int n = 0; n < 4; ++n) s += wo_[n] * fast_tanh(acc[m][n][r] + q_[n]);
      v[m * 16 + r] = s;
    }
  // transpose-reduce over the 32 col-lanes: lane lo ends with full sum of value lo
#pragma unroll
  for (int sdist = 16; sdist >= 1; sdist >>= 1) {
#pragma unroll
    for (int i = 0; i < sdist; ++i) {
      float a = v[i], c = v[i + sdist];
      float keep = (lo & sdist) ? c : a;
      float send = (lo & sdist) ? a : c;
      v[i] = keep + __shfl_xor(send, sdist, 64);
    }
  }
  int rr = lo & 15;
  int row_local = (lo >> 4) * 32 + (rr & 3) + 8 * (rr >> 2) + 4 * hi;  // C/D row map
  int row = rb * 256 + wv * 64 + row_local;
  atomicAdd(&logit[row], v[0]);
}

// ---------------- weights: mask*exp(logit+bo), normalize over L ----------------
__global__ __launch_bounds__(256) void k_weights(const float* __restrict__ mask,
                                                 const float* __restrict__ bo,
                                                 const float* __restrict__ logit,
                                                 float* __restrict__ wout) {
  __shared__ float red[4];
  int b = blockIdx.x, t = threadIdx.x;
  float bov = bo[0];
  float w[8];
  float s = 0.f;
#pragma unroll
  for (int i = 0; i < 8; ++i) {
    int l = t + 256 * i;
    float e = mask[b * LL + l] * __expf(logit[b * LL + l] + bov);
    w[i] = e; s += e;
  }
#pragma unroll
  for (int m = 32; m >= 1; m >>= 1) s += __shfl_xor(s, m, 64);
  int wave = t >> 6, lane = t & 63;
  if (lane == 0) red[wave] = s;
  __syncthreads();
  float inv = 1.0f / (red[0] + red[1] + red[2] + red[3] + 1e-5f);
#pragma unroll
  for (int i = 0; i < 8; ++i) wout[b * LL + t + 256 * i] = w[i] * inv;
}

// ---------------- output from packed ctx: out[b][c] = sum_l w[b][l]*A[l][c] ----
// 128 blocks = 32 b x 4 ks-quarters; 512 thr. Thread owns cols ks*16+hi*8..+8,
// loops 64 tiles; shfl-reduce over lo; lanes lo==0 write directly (no atomics).
__global__ __launch_bounds__(512) void k_output_pk(const uint4* __restrict__ apk,
                                                   const float* __restrict__ wout,
                                                   float* __restrict__ out) {
  int bid = blockIdx.x;
  int b = bid >> 2, q = bid & 3;
  int t = threadIdx.x;
  int lane = t & 63, ks = q * 8 + (t >> 6);
  int lo = lane & 31, hi = lane >> 5;
  const uint4* pa = apk + (size_t)(b * 64) * 2048 + (size_t)ks * 64 + lane;
  const float* wp = wout + b * LL + lo;
  float a8[8] = {0,0,0,0,0,0,0,0};
  for (int gg = 0; gg < 64; ++gg) {
    uint4 u = pa[(size_t)gg * 2048];
    float w = wp[gg * 32];
    unsigned int uu[4] = {u.x, u.y, u.z, u.w};
#pragma unroll
    for (int j = 0; j < 4; ++j) {
      a8[2 * j]     += w * __uint_as_float(uu[j] << 16);
      a8[2 * j + 1] += w * __uint_as_float(uu[j] & 0xffff0000u);
    }
  }
#pragma unroll
  for (int m = 1; m <= 16; m <<= 1)
#pragma unroll
    for (int j = 0; j < 8; ++j) a8[j] += __shfl_xor(a8[j], m, 64);
  if (lo == 0) {
#pragma unroll
    for (int j = 0; j < 8; ++j) out[b * CH + ks * 16 + hi * 8 + j] = a8[j];
  }
}

// ================= fallback path (r6, proven): used if ws too small ==========
__global__ __launch_bounds__(512, 2) void k_logits_lds(const float* __restrict__ ctx,
                                                       const unsigned short* __restrict__ wcbp,
                                                       const float* __restrict__ resqc,
                                                       const float* __restrict__ Wo,
                                                       float* __restrict__ logits) {
  __shared__ unsigned short Alds[2][64 * 520];
  __shared__ float lsum4[4][64];
  const int t = threadIdx.x;
  const int g0 = blockIdx.x * 4;
  if (t < 256) lsum4[t >> 6][t & 63] = 0.f;
  {
    int b = g0 >> 5, row0 = (g0 & 31) << 6;
    const float4* src = (const float4*)(ctx + ((size_t)(b * LL + row0)) * CH);
#pragma unroll
    for (int i = 0; i < 16; ++i) {
      int f = i * 512 + t;
      int r = f >> 7, c4 = f & 127;
      float4 v = src[f];
      uint2 w;
      w.x = cvt_pk_bf16(v.x, v.y);
      w.y = cvt_pk_bf16(v.z, v.w);
      *(uint2*)(Alds[0] + r * 520 + c4 * 4) = w;
    }
  }
  __syncthreads();
  const int wave = t >> 6, lane = t & 63;
  const int lo = lane & 31, hi = lane >> 5;
  const int n0 = wave * 128;
  const uint4* bp = (const uint4*)wcbp + (size_t)(wave * 4) * 2048 + lane;
  float wo_[4];
#pragma unroll
  for (int n = 0; n < 4; ++n) wo_[n] = Wo[n0 + n * 32 + lo];
  for (int tt = 0; tt < 4; ++tt) {
    const int g = g0 + tt;
    const int b = g >> 5, row0 = (g & 31) << 6;
    const int cur = tt & 1;
    if (tt < 3) {
      int gn = g + 1;
      int nb = gn >> 5, nrow0 = (gn & 31) << 6;
      const float4* src = (const float4*)(ctx + ((size_t)(nb * LL + nrow0)) * CH);
#pragma unroll
      for (int i = 0; i < 16; ++i) {
        int f = i * 512 + t;
        int r = f >> 7, c4 = f & 127;
        float4 v = src[f];
        uint2 w;
        w.x = cvt_pk_bf16(v.x, v.y);
        w.y = cvt_pk_bf16(v.z, v.w);
        *(uint2*)(Alds[cur ^ 1] + r * 520 + c4 * 4) = w;
      }
    }
    const char* a0b = (const char*)(Alds[cur]) + lo * 1040 + hi * 16;
    f32x16 acc[2][4];
#pragma unroll
    for (int m = 0; m < 2; ++m)
#pragma unroll
      for (int n = 0; n < 4; ++n) acc[m][n] = (f32x16){0,0,0,0,0,0,0,0,0,0,0,0,0,0,0,0};
#pragma unroll 4
    for (int ks = 0; ks < 32; ++ks) {
      uint4 ub[4];
#pragma unroll
      for (int n = 0; n < 4; ++n) ub[n] = bp[(size_t)n * 2048 + ks * 64];
      bf16x8 fa[2];
#pragma unroll
      for (int m = 0; m < 2; ++m)
        fa[m] = *(const bf16x8*)(a0b + m * (32 * 1040) + ks * 32);
#pragma unroll
      for (int m = 0; m < 2; ++m)
#pragma unroll
        for (int n = 0; n < 4; ++n) {
          bf16x8 fb;
          __builtin_memcpy(&fb, &ub[n], 16);
          acc[m][n] = __builtin_amdgcn_mfma_f32_32x32x16_bf16(fa[m], fb, acc[m][n], 0, 0, 0);
        }
    }
    float q_[4];
#pragma unroll
    for (int n = 0; n < 4; ++n) q_[n] = resqc[b * HH + n0 + n * 32 + lo];
    float v[32];
#pragma unroll
    for (int m = 0; m < 2; ++m)
#pragma unroll
      for (int r = 0; r < 16; ++r) {
        float s = 0.f;
#pragma unroll
        for (int n = 0; n < 4; ++n) s += wo_[n] * fast_tanh(acc[m][n][r] + q_[n]);
        v[m * 16 + r] = s;
      }
#pragma unroll
    for (int sdist = 16; sdist >= 1; sdist >>= 1) {
#pragma unroll
      for (int i = 0; i < sdist; ++i) {
        float a = v[i], c = v[i + sdist];
        float keep = (lo & sdist) ? c : a;
        float send = (lo & sdist) ? a : c;
        v[i] = keep + __shfl_xor(send, sdist, 64);
      }
    }
    int rr = lo & 15;
    int row = ((lo < 16) ? 0 : 32) + (rr & 3) + 8 * (rr >> 2) + 4 * hi;
    atomicAdd(&lsum4[tt][row], v[0]);
    __syncthreads();
    if (t < 64) logits[(size_t)b * LL + row0 + t] = lsum4[tt][t];
  }
}

__global__ __launch_bounds__(256) void k_output_f32(const float* __restrict__ ctx,
                                                    const float* __restrict__ weights,
                                                    float* __restrict__ out) {
  __shared__ float wl[128];
  int bid = blockIdx.x;
  int b = bid >> 4, chunk = bid & 15;
  int t = threadIdx.x;
  int l0 = chunk * 128;
  if (t < 128) wl[t] = weights[b * LL + l0 + t];
  __syncthreads();
  const float2* c2 = (const float2*)(ctx + ((size_t)(b * LL + l0)) * CH) + t;
  float ax = 0.f, ay = 0.f;
#pragma unroll 4
  for (int l = 0; l < 128; ++l) {
    float wv = wl[l];
    float2 v = c2[(size_t)l * (CH / 2)];
    ax += wv * v.x; ay += wv * v.y;
  }
  atomicAdd(&out[b * CH + 2 * t], ax);
  atomicAdd(&out[b * CH + 2 * t + 1], ay);
}

extern "C" void kernel_launch(void* const* d_in, const int* in_sizes, int n_in,
                              void* d_out, int out_size, void* d_ws, size_t ws_size,
                              hipStream_t stream) {
  const float* query = (const float*)d_in[0];
  const float* ctx   = (const float*)d_in[1];
  const float* mask  = (const float*)d_in[2];
  const float* Wq    = (const float*)d_in[3];
  const float* Wc    = (const float*)d_in[4];
  const float* bc    = (const float*)d_in[5];
  const float* Wo    = (const float*)d_in[6];
  const float* bo    = (const float*)d_in[7];
  float* out = (float*)d_out;

  unsigned short* wcbp = (unsigned short*)d_ws;                   // 1 MB packed bf16 Wc
  float* resqc = (float*)((char*)d_ws + (1 << 20));               // 128 KB
  float* logit = (float*)((char*)d_ws + (1 << 20) + (1 << 17));   // 256 KB
  uint4* apk   = (uint4*)((char*)d_ws + (2 << 20));               // 64 MB packed bf16 ctx
  float* wout = out + NB * CH;                                    // final weights slot

  const size_t need = (size_t)(2 << 20) + ((size_t)64 << 20);

  k_resqc<<<128, 256, 0, stream>>>(query, Wq, bc, resqc);
  k_pack_wc<<<256, 256, 0, stream>>>(Wc, wcbp);

  if (ws_size >= need) {
    k_pack_ctx<<<2048, 512, 0, stream>>>(ctx, apk);
    hipMemsetAsync(logit, 0, NB * LL * sizeof(float), stream);
    k_logits_pk<<<2048, 256, 0, stream>>>(apk, (const uint4*)wcbp, resqc, Wo, logit);
    k_weights<<<32, 256, 0, stream>>>(mask, bo, logit, wout);
    k_output_pk<<<128, 512, 0, stream>>>(apk, wout, out);
  } else {
    hipMemsetAsync(out, 0, NB * CH * sizeof(float), stream);
    k_logits_lds<<<256, 512, 0, stream>>>(ctx, wcbp, resqc, Wo, logit);
    k_weights<<<32, 256, 0, stream>>>(mask, bo, logit, wout);
    k_output_f32<<<512, 256, 0, stream>>>(ctx, wout, out);
  }
}